// Round 6
// baseline (56.588 us; speedup 1.0000x reference)
//
#include <hip/hip_runtime.h>

// VoxelQueryAndGrouping — MI355X (gfx950), round 6
// FOUR queries per wave, software-interleaved: all v2p gathers issued
// back-to-back, then all candidate-point gathers, then 4 independent
// ballot/ds_permute chains, then all feature gathers before stores.
// Barrier-free, zero LDS, no pre-kernels.

constexpr int ZG = 21;
constexpr int YG = 400;
constexpr int XG = 352;
constexpr int NS = 16;   // NSAMPLE
constexpr int CF = 32;   // feature channels
constexpr float R2 = 64.0f; // RADIUS^2
constexpr int QPW = 4;   // queries per wave

typedef float v4f __attribute__((ext_vector_type(4)));

__global__ __launch_bounds__(256) void vqg_kernel(
    const int*   __restrict__ new_coords,     // (M,4) [b,z,y,x]
    const float* __restrict__ xyz,            // (N,3)
    const int*   __restrict__ xyz_batch_cnt,  // (B,)
    const float* __restrict__ new_xyz,        // (M,3)
    const float* __restrict__ features,       // (N,CF)
    const int*   __restrict__ v2p,            // (B,ZG,YG,XG)
    float* __restrict__ out_feat,             // (M,CF,NS)
    float* __restrict__ out_xyz,              // (M,3,NS)
    float* __restrict__ out_empty,            // (M,)
    int M)
{
    const int lane = threadIdx.x & 63;
    const int w    = (blockIdx.x * 256 + threadIdx.x) >> 6;  // wave id
    const int mb   = w * QPW;
    if (mb >= M) return;                      // wave-uniform exit

    bool has[QPW];
    #pragma unroll
    for (int q = 0; q < QPW; ++q) has[q] = (mb + q) < M;

    // ---- query descriptors (wave-uniform lines) ----
    int4  qc[QPW];
    float qx[QPW], qy[QPW], qz[QPW];
    int   boff[QPW];
    #pragma unroll
    for (int q = 0; q < QPW; ++q) {
        const int m = has[q] ? (mb + q) : mb;
        qc[q] = *reinterpret_cast<const int4*>(new_coords + (size_t)m * 4);
        qx[q] = new_xyz[m * 3 + 0];
        qy[q] = new_xyz[m * 3 + 1];
        qz[q] = new_xyz[m * 3 + 2];
        int bo = 0;
        for (int i = 0; i < qc[q].x; ++i) bo += xyz_batch_cnt[i];
        boff[q] = bo;
    }

    // ---- neighbor decode (shared) ----
    const int n1 = 64 + lane;
    const int dz0 = lane / 25 - 2, dy0 = (lane / 5) % 5 - 2, dx0 = lane % 5 - 2;
    const int dz1 = n1 / 25 - 2,   dy1 = (n1 / 5) % 5 - 2,   dx1 = n1 % 5 - 2;
    const bool in1 = (n1 < 125);

    // ---- issue ALL v2p gathers (2*QPW loads back-to-back) ----
    int pidx[QPW][2];
    #pragma unroll
    for (int q = 0; q < QPW; ++q) {
        const int* __restrict__ gb = v2p + (size_t)qc[q].x * (ZG * YG * XG);
        pidx[q][0] = -1;
        pidx[q][1] = -1;
        {
            const int z = qc[q].y + dz0, y = qc[q].z + dy0, x = qc[q].w + dx0;
            if ((unsigned)z < (unsigned)ZG && (unsigned)y < (unsigned)YG &&
                (unsigned)x < (unsigned)XG)
                pidx[q][0] = gb[((size_t)z * YG + y) * XG + x];
        }
        {
            const int z = qc[q].y + dz1, y = qc[q].z + dy1, x = qc[q].w + dx1;
            if (in1 && (unsigned)z < (unsigned)ZG && (unsigned)y < (unsigned)YG &&
                (unsigned)x < (unsigned)XG)
                pidx[q][1] = gb[((size_t)z * YG + y) * XG + x];
        }
    }

    // ---- issue ALL candidate-point gathers ----
    float px[QPW][2], py[QPW][2], pz[QPW][2];
    #pragma unroll
    for (int q = 0; q < QPW; ++q) {
        #pragma unroll
        for (int p = 0; p < 2; ++p) {
            px[q][p] = 0.f; py[q][p] = 0.f; pz[q][p] = 0.f;
            if (pidx[q][p] >= 0) {
                const float* r = xyz + (size_t)pidx[q][p] * 3;
                px[q][p] = r[0]; py[q][p] = r[1]; pz[q][p] = r[2];
            }
        }
    }

    // ---- distances (exact reference association, no FMA) ----
    bool val[QPW][2];
    #pragma unroll
    for (int q = 0; q < QPW; ++q) {
        #pragma unroll
        for (int p = 0; p < 2; ++p) {
            bool v = false;
            if (pidx[q][p] >= 0) {
                const float dx = px[q][p] - qx[q];
                const float dy = py[q][p] - qy[q];
                const float dz = pz[q][p] - qz[q];
                v = __fadd_rn(__fadd_rn(__fmul_rn(dx, dx), __fmul_rn(dy, dy)),
                              __fmul_rn(dz, dz)) < R2;
            }
            val[q][p] = v;
        }
    }

    const unsigned long long below = (1ull << lane) - 1ull;
    const int junk = (16 + (lane & 31)) << 2;

    // ---- per-query ordered slot scatter (register-only) ----
    int cnt[QPW], gfin[QPW];
    #pragma unroll
    for (int q = 0; q < QPW; ++q) {
        const unsigned long long bal0 = __ballot(val[q][0]);
        const unsigned long long bal1 = __ballot(val[q][1]);
        const int c0   = (int)__popcll(bal0);
        cnt[q] = c0 + (int)__popcll(bal1);
        const int pos0 = (int)__popcll(bal0 & below);
        const int pos1 = c0 + (int)__popcll(bal1 & below);
        const int addr0 = (val[q][0] && pos0 < NS) ? (pos0 << 2) : junk;
        const int addr1 = (val[q][1] && pos1 < NS) ? (pos1 << 2) : junk;
        const int perm0 = __builtin_amdgcn_ds_permute(addr0, pidx[q][0]);
        const int perm1 = __builtin_amdgcn_ds_permute(addr1, pidx[q][1]);
        const int sel   = (lane < c0) ? perm0 : perm1;
        const int first = __shfl(sel, 0);
        const int c16   = cnt[q] < NS ? cnt[q] : NS;
        gfin[q] = (cnt[q] == 0) ? boff[q] : (((lane & 15) < c16) ? sel : first);
    }

    // ---- grouped_xyz + empty ----
    {
        const int s = lane & 15;
        const int d = lane >> 4;
        #pragma unroll
        for (int q = 0; q < QPW; ++q) {
            if (!has[q]) continue;
            const int m = mb + q;
            if (lane < 48) {
                const int row = __shfl(gfin[q], s);
                __builtin_nontemporal_store(xyz[(size_t)row * 3 + d],
                                            out_xyz + (size_t)m * 48 + d * 16 + s);
            }
            if (lane == 0)
                __builtin_nontemporal_store(cnt[q] == 0 ? 1.0f : 0.0f, out_empty + m);
        }
    }

    // ---- grouped_features: all gathers issued, then all stores ----
    const int s0 = (lane & 3) << 2;
    const int cA = (lane >> 2);        // channel for k=0
    int rr[QPW][4];
    #pragma unroll
    for (int q = 0; q < QPW; ++q) {
        rr[q][0] = __shfl(gfin[q], s0 + 0);
        rr[q][1] = __shfl(gfin[q], s0 + 1);
        rr[q][2] = __shfl(gfin[q], s0 + 2);
        rr[q][3] = __shfl(gfin[q], s0 + 3);
    }
    v4f vv[QPW][2];
    #pragma unroll
    for (int q = 0; q < QPW; ++q) {
        #pragma unroll
        for (int k = 0; k < 2; ++k) {
            const int c = k * 16 + cA;
            vv[q][k][0] = features[(size_t)rr[q][0] * CF + c];
            vv[q][k][1] = features[(size_t)rr[q][1] * CF + c];
            vv[q][k][2] = features[(size_t)rr[q][2] * CF + c];
            vv[q][k][3] = features[(size_t)rr[q][3] * CF + c];
        }
    }
    #pragma unroll
    for (int q = 0; q < QPW; ++q) {
        if (!has[q]) continue;
        float* __restrict__ of = out_feat + (size_t)(mb + q) * (CF * NS);
        #pragma unroll
        for (int k = 0; k < 2; ++k) {
            __builtin_nontemporal_store(
                vv[q][k], reinterpret_cast<v4f*>(of + k * 256 + (lane << 2)));
        }
    }
}

extern "C" void kernel_launch(void* const* d_in, const int* in_sizes, int n_in,
                              void* d_out, int out_size, void* d_ws, size_t ws_size,
                              hipStream_t stream) {
    const int*   new_coords    = (const int*)d_in[0];
    const float* xyz           = (const float*)d_in[1];
    const int*   xyz_batch_cnt = (const int*)d_in[2];
    const float* new_xyz       = (const float*)d_in[3];
    // d_in[4] = new_xyz_batch_cnt (unused)
    const float* features      = (const float*)d_in[5];
    const int*   v2p           = (const int*)d_in[6];

    const int M = in_sizes[0] / 4;

    float* out_feat  = (float*)d_out;                       // M*CF*NS
    float* out_xyz   = out_feat + (size_t)M * CF * NS;      // M*3*NS
    float* out_empty = out_xyz + (size_t)M * 3 * NS;        // M

    const int waves  = (M + QPW - 1) / QPW;   // 4 queries per wave
    const int blocks = (waves + 3) / 4;       // 4 waves per block
    vqg_kernel<<<blocks, 256, 0, stream>>>(
        new_coords, xyz, xyz_batch_cnt, new_xyz, features, v2p,
        out_feat, out_xyz, out_empty, M);
}